// Round 5
// baseline (190.105 us; speedup 1.0000x reference)
//
#include <hip/hip_runtime.h>
#include <math.h>

#define D_INNER 5120
#define DT_RANK 160
#define N_STATE 16
#define BATCH   256
#define KTOT    192               // 160 (dt_low) | 16 (B) | 16 (C)

// ---- K1 config: 256-thr blocks, 4 waves x 40-dd chunks, intra-block reduce ----
#define BGRP    8                 // batches per block
#define NBG     (BATCH / BGRP)    // 32
#define DDBLK   160               // dd per block (4 waves x 40)
#define NDDB    (D_INNER / DDBLK) // 32 -> SPLIT_P = 32 partials
#define SPLIT   32

// ---- workspace layout (float offsets) ----
#define OFF_T     0
#define SZ_T      (BATCH * KTOT)                  // 49,152
#define OFF_P     (OFF_T + SZ_T)
#define SZ_P      (SPLIT * BATCH * KTOT)          // 1,572,864 (6.3 MB)
#define OFF_DELTA OFF_P                           // alias: P dead after K2
// delta needs BATCH*D_INNER = 1,310,720 < SZ_P.

// ---------------------------------------------------------------------------
// K1: projection GEMM partials. Block = 256 thr (4 waves); block covers 8
// batches x 160 dd; wave w handles dd sub-chunk [40w, 40w+40). x staged in
// LDS row-major xs[b][160]; intra-block reduce of the 4 waves -> P[s][b][k].
// 1024 blocks = 16 waves/CU.
// ---------------------------------------------------------------------------
__global__ __launch_bounds__(256) void k1_gemm(const float* __restrict__ x,
                                               const float* __restrict__ Wdtlow,
                                               const float* __restrict__ WB,
                                               const float* __restrict__ WC,
                                               float* __restrict__ ws) {
    __shared__ float lds[4 * BGRP * KTOT];   // 6144 floats = 24 KB
    const int tid  = threadIdx.x;
    const int lane = tid & 63;
    const int wv   = tid >> 6;               // wave 0..3
    const int b0   = blockIdx.x * BGRP;
    const int ddB  = blockIdx.y * DDBLK;

    // stage x[b0..+7][ddB..+159] -> xs[i][c] (row-major, 320 float4, linear)
    float* xs = lds;
    for (int j = tid; j < (BGRP * DDBLK) / 4; j += 256) {   // 320 float4
        int i  = j / (DDBLK / 4);
        int c4 = j % (DDBLK / 4);
        float4 v = *(const float4*)(x + (size_t)(b0 + i) * D_INNER + ddB + c4 * 4);
        *(float4*)(xs + i * DDBLK + c4 * 4) = v;
    }
    __syncthreads();

    const int dd0 = wv * 40;                 // this wave's chunk within block
    const float* p0 = Wdtlow + (size_t)(ddB + dd0) * DT_RANK + lane;
    const float* p1 = p0 + 64;
    const float* p2;
    int st2;
    if (lane < 32)      { p2 = p0 + 128;                                          st2 = DT_RANK; }
    else if (lane < 48) { p2 = WB + (size_t)(ddB + dd0) * N_STATE + (lane - 32);  st2 = N_STATE; }
    else                { p2 = WC + (size_t)(ddB + dd0) * N_STATE + (lane - 48);  st2 = N_STATE; }

    float acc0[BGRP], acc1[BGRP], acc2[BGRP];
#pragma unroll
    for (int i = 0; i < BGRP; ++i) { acc0[i] = 0.f; acc1[i] = 0.f; acc2[i] = 0.f; }

#pragma unroll 2
    for (int g = 0; g < 10; ++g) {           // 4 dd per group
        float w0[4], w1[4], w2[4];
#pragma unroll
        for (int u = 0; u < 4; ++u) {
            int dd = g * 4 + u;
            w0[u] = p0[(size_t)dd * DT_RANK];
            w1[u] = p1[(size_t)dd * DT_RANK];
            w2[u] = p2[(size_t)dd * st2];
        }
#pragma unroll
        for (int i = 0; i < BGRP; ++i) {
            float4 xv = *(const float4*)(xs + i * DDBLK + dd0 + g * 4);  // broadcast b128
            acc0[i] += xv.x * w0[0] + xv.y * w0[1] + xv.z * w0[2] + xv.w * w0[3];
            acc1[i] += xv.x * w1[0] + xv.y * w1[1] + xv.z * w1[2] + xv.w * w1[3];
            acc2[i] += xv.x * w2[0] + xv.y * w2[1] + xv.z * w2[2] + xv.w * w2[3];
        }
    }
    __syncthreads();                         // xs dead; reuse lds for reduce

#pragma unroll
    for (int i = 0; i < BGRP; ++i) {
        float* r = lds + wv * (BGRP * KTOT) + i * KTOT;
        r[lane]       = acc0[i];
        r[lane + 64]  = acc1[i];
        r[lane + 128] = acc2[i];
    }
    __syncthreads();

    float* P = ws + OFF_P + (size_t)blockIdx.y * (BATCH * KTOT) + (size_t)b0 * KTOT;
#pragma unroll
    for (int r = 0; r < 6; ++r) {
        int idx = tid + r * 256;             // 0..1535
        float v = lds[idx] + lds[idx + 1536] + lds[idx + 3072] + lds[idx + 4608];
        P[idx] = v;
    }
}

// ---------------------------------------------------------------------------
// K2: reduce split-K partials -> T[256][192]
// ---------------------------------------------------------------------------
__global__ __launch_bounds__(256) void k2_reduce(float* __restrict__ ws) {
    int g = blockIdx.x * 256 + threadIdx.x;    // < 49152
    const float* P = ws + OFF_P;
    float a = 0.f;
#pragma unroll
    for (int s = 0; s < SPLIT; ++s) a += P[(size_t)s * (BATCH * KTOT) + g];
    ws[OFF_T + g] = a;
}

// ---------------------------------------------------------------------------
// K3a: delta GEMM + softplus. BT=8 batches/block, grid (20,32)=640 blocks.
// ts[k*8+b]: linear staging writes, 2x b128 broadcast reads per k.
// ---------------------------------------------------------------------------
#define K3A_BT 8
__global__ __launch_bounds__(256) void k3a_delta(const float* __restrict__ Wdt,
                                                 const float* __restrict__ b_dt,
                                                 float* __restrict__ ws) {
    __shared__ float ts[DT_RANK * K3A_BT];     // 1280 floats = 5 KB
    const int tid = threadIdx.x;
    const int d   = blockIdx.x * 256 + tid;
    const int b0  = blockIdx.y * K3A_BT;
    const float* T = ws + OFF_T;

    for (int j = tid; j < DT_RANK * K3A_BT; j += 256) {
        int b = j & (K3A_BT - 1);
        int k = j >> 3;
        ts[j] = T[(size_t)(b0 + b) * KTOT + k];   // ts[k*8+b]
    }
    __syncthreads();

    float acc[K3A_BT];
#pragma unroll
    for (int i = 0; i < K3A_BT; ++i) acc[i] = 0.f;

#pragma unroll 4
    for (int k = 0; k < DT_RANK; ++k) {
        float w = Wdt[(size_t)k * D_INNER + d];
        float4 t0 = *(const float4*)(ts + k * 8);
        float4 t1 = *(const float4*)(ts + k * 8 + 4);
        acc[0] += t0.x * w; acc[1] += t0.y * w; acc[2] += t0.z * w; acc[3] += t0.w * w;
        acc[4] += t1.x * w; acc[5] += t1.y * w; acc[6] += t1.z * w; acc[7] += t1.w * w;
    }

    const float bv = b_dt[d];
    float* delta = ws + OFF_DELTA;
#pragma unroll
    for (int i = 0; i < K3A_BT; ++i) {
        float v  = acc[i] + bv;
        float dl = (v > 20.f) ? v : log1pf(__expf(v));
        delta[(size_t)(b0 + i) * D_INNER + d] = dl;
    }
}

// ---------------------------------------------------------------------------
// K3b: streaming state update + output, COALESCED h0.
// 4 lanes per d (nq = tid&3 = which float4 of the 16-float state row).
// Wave's h0/A loads are contiguous 1KB per instruction (lane-consecutive 16B).
// y reduced over the 4 lanes via shfl_xor; lane nq==0 writes out.
// Block covers 64 d x 1 batch; grid (80, 256).
// ---------------------------------------------------------------------------
__global__ __launch_bounds__(256) void k3b_scan(const float* __restrict__ x,
                                                const float* __restrict__ A,
                                                const float* __restrict__ Dv,
                                                const float* __restrict__ h0,
                                                const float* __restrict__ ws,
                                                float* __restrict__ out) {
    const int tid  = threadIdx.x;
    const int dsub = tid >> 2;           // 0..63
    const int nq   = tid & 3;            // which float4 of the state row
    const int d    = blockIdx.x * 64 + dsub;
    const int b    = blockIdx.y;

    const float* Tb = ws + OFF_T + (size_t)b * KTOT;   // uniform row -> s_loads
    float sbc = 0.f;
#pragma unroll
    for (int n = 0; n < N_STATE; ++n) sbc += Tb[160 + n] * Tb[176 + n];
    float cp0 = Tb[176 + nq * 4 + 0];
    float cp1 = Tb[176 + nq * 4 + 1];
    float cp2 = Tb[176 + nq * 4 + 2];
    float cp3 = Tb[176 + nq * 4 + 3];

    const float delta = ws[OFF_DELTA + (size_t)b * D_INNER + d];  // 4 lanes share
    float4 a = ((const float4*)(A + (size_t)d * N_STATE))[nq];    // coalesced
    float4 h = ((const float4*)(h0 + ((size_t)b * D_INNER + d) * N_STATE))[nq]; // coalesced 1KB/wave

    float y = __expf(delta * a.x) * h.x * cp0
            + __expf(delta * a.y) * h.y * cp1
            + __expf(delta * a.z) * h.z * cp2
            + __expf(delta * a.w) * h.w * cp3;
    y += __shfl_xor(y, 1);
    y += __shfl_xor(y, 2);

    if (nq == 0) {
        float xv = x[(size_t)b * D_INNER + d];
        out[(size_t)b * D_INNER + d] = xv * (Dv[d] + delta * sbc) + y;
    }
}

// ---------------------------------------------------------------------------
extern "C" void kernel_launch(void* const* d_in, const int* in_sizes, int n_in,
                              void* d_out, int out_size, void* d_ws, size_t ws_size,
                              hipStream_t stream) {
    const float* x      = (const float*)d_in[0];
    const float* Wdtlow = (const float*)d_in[1];
    const float* Wdt    = (const float*)d_in[2];
    const float* bdt    = (const float*)d_in[3];
    const float* WB     = (const float*)d_in[4];
    const float* WC     = (const float*)d_in[5];
    const float* A      = (const float*)d_in[6];
    const float* Dv     = (const float*)d_in[7];
    const float* h0     = (const float*)d_in[8];
    float* ws  = (float*)d_ws;
    float* out = (float*)d_out;

    // K1: projection GEMM partials (1024 blocks, 16 waves/CU)
    hipLaunchKernelGGL(k1_gemm, dim3(NBG, NDDB), dim3(256), 0, stream,
                       x, Wdtlow, WB, WC, ws);
    // K2: reduce partials -> T[256][192]
    hipLaunchKernelGGL(k2_reduce, dim3((BATCH * KTOT) / 256), dim3(256), 0, stream, ws);
    // K3a: delta GEMM + softplus -> delta[256][5120]  (640 blocks)
    hipLaunchKernelGGL(k3a_delta, dim3(D_INNER / 256, BATCH / K3A_BT), dim3(256),
                       0, stream, Wdt, bdt, ws);
    // K3b: streaming state update + output (coalesced h0; 20480 blocks)
    hipLaunchKernelGGL(k3b_scan, dim3(D_INNER / 64, BATCH), dim3(256), 0, stream,
                       x, A, Dv, h0, ws, out);
}

// Round 7
// 183.145 us; speedup vs baseline: 1.0380x; 1.0380x over previous
//
#include <hip/hip_runtime.h>
#include <math.h>

#define D_INNER 5120
#define DT_RANK 160
#define N_STATE 16
#define BATCH   256
#define KTOT    192               // 160 (dt_low) | 16 (B) | 16 (C)

// ---- K1 config: 256-thr blocks, 4 waves x 40-dd chunks, intra-block reduce ----
#define BGRP    8                 // batches per block
#define NBG     (BATCH / BGRP)    // 32
#define DDBLK   160               // dd per block (4 waves x 40)
#define NDDB    (D_INNER / DDBLK) // 32 -> SPLIT partials
#define SPLIT   32

// ---- K3 config ----
#define K3_BT   8                 // batches per block

// ---- workspace layout (float offsets) ----
#define OFF_T     0
#define SZ_T      (BATCH * KTOT)                  // 49,152
#define OFF_P     (OFF_T + SZ_T)
#define SZ_P      (SPLIT * BATCH * KTOT)          // 1,572,864 (6.3 MB)

// ---------------------------------------------------------------------------
// K1: projection GEMM partials. Block = 256 thr (4 waves); block covers 8
// batches x 160 dd; wave w handles dd sub-chunk [40w, 40w+40). x staged in
// LDS row-major xs[b][160]; intra-block reduce of the 4 waves -> P[s][b][k].
// 1024 blocks = 16 waves/CU.
// ---------------------------------------------------------------------------
__global__ __launch_bounds__(256) void k1_gemm(const float* __restrict__ x,
                                               const float* __restrict__ Wdtlow,
                                               const float* __restrict__ WB,
                                               const float* __restrict__ WC,
                                               float* __restrict__ ws) {
    __shared__ float lds[4 * BGRP * KTOT];   // 6144 floats = 24 KB
    const int tid  = threadIdx.x;
    const int lane = tid & 63;
    const int wv   = tid >> 6;               // wave 0..3
    const int b0   = blockIdx.x * BGRP;
    const int ddB  = blockIdx.y * DDBLK;

    // stage x[b0..+7][ddB..+159] -> xs[i][c] (row-major, 320 float4, linear)
    float* xs = lds;
    for (int j = tid; j < (BGRP * DDBLK) / 4; j += 256) {   // 320 float4
        int i  = j / (DDBLK / 4);
        int c4 = j % (DDBLK / 4);
        float4 v = *(const float4*)(x + (size_t)(b0 + i) * D_INNER + ddB + c4 * 4);
        *(float4*)(xs + i * DDBLK + c4 * 4) = v;
    }
    __syncthreads();

    const int dd0 = wv * 40;                 // this wave's chunk within block
    const float* p0 = Wdtlow + (size_t)(ddB + dd0) * DT_RANK + lane;
    const float* p1 = p0 + 64;
    const float* p2;
    int st2;
    if (lane < 32)      { p2 = p0 + 128;                                          st2 = DT_RANK; }
    else if (lane < 48) { p2 = WB + (size_t)(ddB + dd0) * N_STATE + (lane - 32);  st2 = N_STATE; }
    else                { p2 = WC + (size_t)(ddB + dd0) * N_STATE + (lane - 48);  st2 = N_STATE; }

    float acc0[BGRP], acc1[BGRP], acc2[BGRP];
#pragma unroll
    for (int i = 0; i < BGRP; ++i) { acc0[i] = 0.f; acc1[i] = 0.f; acc2[i] = 0.f; }

#pragma unroll 2
    for (int g = 0; g < 10; ++g) {           // 4 dd per group
        float w0[4], w1[4], w2[4];
#pragma unroll
        for (int u = 0; u < 4; ++u) {
            int dd = g * 4 + u;
            w0[u] = p0[(size_t)dd * DT_RANK];
            w1[u] = p1[(size_t)dd * DT_RANK];
            w2[u] = p2[(size_t)dd * st2];
        }
#pragma unroll
        for (int i = 0; i < BGRP; ++i) {
            float4 xv = *(const float4*)(xs + i * DDBLK + dd0 + g * 4);  // broadcast b128
            acc0[i] += xv.x * w0[0] + xv.y * w0[1] + xv.z * w0[2] + xv.w * w0[3];
            acc1[i] += xv.x * w1[0] + xv.y * w1[1] + xv.z * w1[2] + xv.w * w1[3];
            acc2[i] += xv.x * w2[0] + xv.y * w2[1] + xv.z * w2[2] + xv.w * w2[3];
        }
    }
    __syncthreads();                         // xs dead; reuse lds for reduce

#pragma unroll
    for (int i = 0; i < BGRP; ++i) {
        float* r = lds + wv * (BGRP * KTOT) + i * KTOT;
        r[lane]       = acc0[i];
        r[lane + 64]  = acc1[i];
        r[lane + 128] = acc2[i];
    }
    __syncthreads();

    float* P = ws + OFF_P + (size_t)blockIdx.y * (BATCH * KTOT) + (size_t)b0 * KTOT;
#pragma unroll
    for (int r = 0; r < 6; ++r) {
        int idx = tid + r * 256;             // 0..1535
        P[idx] = lds[idx] + lds[idx + 1536] + lds[idx + 3072] + lds[idx + 4608];
    }
}

// ---------------------------------------------------------------------------
// K2: reduce split-K partials -> T[256][192]
// ---------------------------------------------------------------------------
__global__ __launch_bounds__(256) void k2_reduce(float* __restrict__ ws) {
    int g = blockIdx.x * 256 + threadIdx.x;    // < 49152
    const float* P = ws + OFF_P;
    float a = 0.f;
#pragma unroll
    for (int s = 0; s < SPLIT; ++s) a += P[(size_t)s * (BATCH * KTOT) + g];
    ws[OFF_T + g] = a;
}

// ---------------------------------------------------------------------------
// K3 (fused k3a+k3b): delta GEMM + softplus in REGISTERS, then SSM scan + out.
// No delta round-trip through global. Block = 256 thr, covers 256 d x 8
// batches; grid (20, 32) = 640 blocks (10 waves/CU).
//   ts[k*8+b]: linear staging writes, 2x b128 broadcast reads per k.
//   out = x*(D + delta*sum_n Bp_n*Cp_n) + sum_n exp(delta*A_n)*h0_n*Cp_n
// ---------------------------------------------------------------------------
__global__ __launch_bounds__(256) void k3_fused(const float* __restrict__ Wdt,
                                                const float* __restrict__ b_dt,
                                                const float* __restrict__ x,
                                                const float* __restrict__ A,
                                                const float* __restrict__ Dv,
                                                const float* __restrict__ h0,
                                                const float* __restrict__ ws,
                                                float* __restrict__ out) {
    __shared__ float ts[DT_RANK * K3_BT];     // 1280 floats = 5 KB
    const int tid = threadIdx.x;
    const int d   = blockIdx.x * 256 + tid;
    const int b0  = blockIdx.y * K3_BT;
    const float* T = ws + OFF_T;

    for (int j = tid; j < DT_RANK * K3_BT; j += 256) {
        int b = j & (K3_BT - 1);
        int k = j >> 3;
        ts[j] = T[(size_t)(b0 + b) * KTOT + k];   // ts[k*8+b]
    }
    __syncthreads();

    float acc[K3_BT];
#pragma unroll
    for (int i = 0; i < K3_BT; ++i) acc[i] = 0.f;

#pragma unroll 4
    for (int k = 0; k < DT_RANK; ++k) {
        float w = Wdt[(size_t)k * D_INNER + d];
        float4 t0 = *(const float4*)(ts + k * 8);
        float4 t1 = *(const float4*)(ts + k * 8 + 4);
        acc[0] += t0.x * w; acc[1] += t0.y * w; acc[2] += t0.z * w; acc[3] += t0.w * w;
        acc[4] += t1.x * w; acc[5] += t1.y * w; acc[6] += t1.z * w; acc[7] += t1.w * w;
    }

    const float bv = b_dt[d];
    const float Dd = Dv[d];
    const float4* a4 = (const float4*)(A + (size_t)d * N_STATE);
    float4 a0 = a4[0], a1 = a4[1], a2 = a4[2], a3 = a4[3];

#pragma unroll
    for (int i = 0; i < K3_BT; ++i) {
        const int b = b0 + i;
        float v     = acc[i] + bv;
        float delta = (v > 20.f) ? v : log1pf(__expf(v));

        const float* Tb = T + (size_t)b * KTOT;   // uniform row -> s_loads
        float sbc = 0.f;
#pragma unroll
        for (int n = 0; n < N_STATE; ++n) sbc += Tb[160 + n] * Tb[176 + n];

        const float4* h4 = (const float4*)(h0 + ((size_t)b * D_INNER + d) * N_STATE);
        float4 h_0 = h4[0], h_1 = h4[1], h_2 = h4[2], h_3 = h4[3];

        float y = 0.f;
        y += __expf(delta * a0.x) * h_0.x * Tb[176 + 0];
        y += __expf(delta * a0.y) * h_0.y * Tb[176 + 1];
        y += __expf(delta * a0.z) * h_0.z * Tb[176 + 2];
        y += __expf(delta * a0.w) * h_0.w * Tb[176 + 3];
        y += __expf(delta * a1.x) * h_1.x * Tb[176 + 4];
        y += __expf(delta * a1.y) * h_1.y * Tb[176 + 5];
        y += __expf(delta * a1.z) * h_1.z * Tb[176 + 6];
        y += __expf(delta * a1.w) * h_1.w * Tb[176 + 7];
        y += __expf(delta * a2.x) * h_2.x * Tb[176 + 8];
        y += __expf(delta * a2.y) * h_2.y * Tb[176 + 9];
        y += __expf(delta * a2.z) * h_2.z * Tb[176 + 10];
        y += __expf(delta * a2.w) * h_2.w * Tb[176 + 11];
        y += __expf(delta * a3.x) * h_3.x * Tb[176 + 12];
        y += __expf(delta * a3.y) * h_3.y * Tb[176 + 13];
        y += __expf(delta * a3.z) * h_3.z * Tb[176 + 14];
        y += __expf(delta * a3.w) * h_3.w * Tb[176 + 15];

        float xv = x[(size_t)b * D_INNER + d];
        out[(size_t)b * D_INNER + d] = xv * (Dd + delta * sbc) + y;
    }
}

// ---------------------------------------------------------------------------
extern "C" void kernel_launch(void* const* d_in, const int* in_sizes, int n_in,
                              void* d_out, int out_size, void* d_ws, size_t ws_size,
                              hipStream_t stream) {
    const float* x      = (const float*)d_in[0];
    const float* Wdtlow = (const float*)d_in[1];
    const float* Wdt    = (const float*)d_in[2];
    const float* bdt    = (const float*)d_in[3];
    const float* WB     = (const float*)d_in[4];
    const float* WC     = (const float*)d_in[5];
    const float* A      = (const float*)d_in[6];
    const float* Dv     = (const float*)d_in[7];
    const float* h0     = (const float*)d_in[8];
    float* ws  = (float*)d_ws;
    float* out = (float*)d_out;

    // K1: projection GEMM partials (1024 blocks, 16 waves/CU)
    hipLaunchKernelGGL(k1_gemm, dim3(NBG, NDDB), dim3(256), 0, stream,
                       x, Wdtlow, WB, WC, ws);
    // K2: reduce partials -> T[256][192]
    hipLaunchKernelGGL(k2_reduce, dim3((BATCH * KTOT) / 256), dim3(256), 0, stream, ws);
    // K3: delta GEMM + softplus (regs) + SSM scan + output (640 blocks)
    hipLaunchKernelGGL(k3_fused, dim3(D_INNER / 256, BATCH / K3_BT), dim3(256),
                       0, stream, Wdt, bdt, x, A, Dv, h0, ws, out);
}